// Round 4
// baseline (1754.734 us; speedup 1.0000x reference)
//
#include <hip/hip_runtime.h>
#include <hip/hip_bf16.h>
#include <hip/hip_fp16.h>

#define N_NODES 20000
#define N_EDGES 640000
#define N_HIDDEN 128
#define EDGE_DIM 8
#define NODE_DIM 16
#define N_BLOCKS 15
#define N_BINARY 10

typedef __attribute__((ext_vector_type(8))) _Float16 f16x8;
typedef __attribute__((ext_vector_type(4))) float f32x4;
typedef unsigned int uint;
typedef unsigned short ushort;

union U2H {
  uint u;
  __half2 h;
};
static __device__ __forceinline__ __half2 u2h2(uint u) {
  U2H c; c.u = u; return c.h;
}
static __device__ __forceinline__ ushort f2h_bits(float f) {
  union { _Float16 h; ushort u; } c;
  c.h = (_Float16)f;
  return c.u;
}

// ---- embed: h = log(x+1) @ embW + embB ; x2p = packed f16(h/std) -----------
__global__ void k_embed(const float* __restrict__ x, const float* __restrict__ eW,
                        const float* __restrict__ ebias, float* __restrict__ h,
                        uint* __restrict__ x2p) {
  int wid = (blockIdx.x * blockDim.x + threadIdx.x) >> 6;
  int lane = threadIdx.x & 63;
  if (wid >= N_NODES) return;
  float xl[NODE_DIM];
#pragma unroll
  for (int k = 0; k < NODE_DIM; k++) xl[k] = logf(x[wid * NODE_DIM + k] + 1.0f);
  int c0 = lane, c1 = lane + 64;
  float h0 = ebias[c0], h1 = ebias[c1];
#pragma unroll
  for (int k = 0; k < NODE_DIM; k++) {
    h0 += xl[k] * eW[k * N_HIDDEN + c0];
    h1 += xl[k] * eW[k * N_HIDDEN + c1];
  }
  float ss = h0 + h1, s2 = h0 * h0 + h1 * h1;
#pragma unroll
  for (int m = 1; m < 64; m <<= 1) {
    ss += __shfl_xor(ss, m);
    s2 += __shfl_xor(s2, m);
  }
  float var = (s2 - ss * ss * (1.0f / 128.0f)) * (1.0f / 127.0f);
  float inv = 1.0f / sqrtf(var);
  size_t o = (size_t)wid * N_HIDDEN;
  h[o + c0] = h0;
  h[o + c1] = h1;
  uint pk = (uint)f2h_bits(h0 * inv) | ((uint)f2h_bits(h1 * inv) << 16);
  x2p[(size_t)wid * 64 + lane] = pk;
}

// ---------------- CSR build ----------------
__global__ void k_count(const int* __restrict__ ei, int* __restrict__ deg) {
  int e = blockIdx.x * blockDim.x + threadIdx.x;
  if (e < N_EDGES) atomicAdd(&deg[ei[N_EDGES + e]], 1);
}

__global__ __launch_bounds__(1024) void k_scan(const int* __restrict__ deg,
                                               int* __restrict__ off,
                                               int* __restrict__ cur) {
  __shared__ int wsum[16];
  int t = threadIdx.x;
  int lane = t & 63, w = t >> 6;
  int base = t * 20;
  int loc[20];
  int s = 0;
#pragma unroll
  for (int i = 0; i < 20; i++) {
    int idx = base + i;
    int d = (idx < N_NODES) ? deg[idx] : 0;
    loc[i] = s;
    s += d;
  }
  int incl = s;
#pragma unroll
  for (int m = 1; m < 64; m <<= 1) {
    int o = __shfl_up(incl, m);
    if (lane >= m) incl += o;
  }
  if (lane == 63) wsum[w] = incl;
  __syncthreads();
  if (w == 0) {
    int xv = (lane < 16) ? wsum[lane] : 0;
#pragma unroll
    for (int m = 1; m < 16; m <<= 1) {
      int o = __shfl_up(xv, m);
      if (lane >= m) xv += o;
    }
    if (lane < 16) wsum[lane] = xv;
  }
  __syncthreads();
  int woff = (w == 0) ? 0 : wsum[w - 1];
  int texcl = woff + incl - s;
#pragma unroll
  for (int i = 0; i < 20; i++) {
    int idx = base + i;
    if (idx < N_NODES) {
      int v = texcl + loc[i];
      off[idx] = v;
      cur[idx] = v;
    }
  }
  if (t == 0) off[N_NODES] = wsum[15];
}

// permute edges dst-sorted; srcoff = src*64 (dword row offset);
// ea2[pos][k] = splatted half2(e_k, e_k), e = log(edge_attr+1)
__global__ void k_permute(const int* __restrict__ ei, const float* __restrict__ eattr,
                          int* __restrict__ cur, uint* __restrict__ srcoff,
                          uint* __restrict__ ea2) {
  int e = blockIdx.x * blockDim.x + threadIdx.x;
  if (e >= N_EDGES) return;
  int d = ei[N_EDGES + e];
  int s = ei[e];
  int pos = atomicAdd(&cur[d], 1);
  srcoff[pos] = (uint)s * 64u;
  const float4* ap = (const float4*)(eattr + (size_t)e * 8);
  float4 a0 = ap[0], a1 = ap[1];
  uint* dp = ea2 + (size_t)pos * 8;
  ushort b;
  b = f2h_bits(logf(a0.x + 1.0f)); dp[0] = (uint)b | ((uint)b << 16);
  b = f2h_bits(logf(a0.y + 1.0f)); dp[1] = (uint)b | ((uint)b << 16);
  b = f2h_bits(logf(a0.z + 1.0f)); dp[2] = (uint)b | ((uint)b << 16);
  b = f2h_bits(logf(a0.w + 1.0f)); dp[3] = (uint)b | ((uint)b << 16);
  b = f2h_bits(logf(a1.x + 1.0f)); dp[4] = (uint)b | ((uint)b << 16);
  b = f2h_bits(logf(a1.y + 1.0f)); dp[5] = (uint)b | ((uint)b << 16);
  b = f2h_bits(logf(a1.z + 1.0f)); dp[6] = (uint)b | ((uint)b << 16);
  b = f2h_bits(logf(a1.w + 1.0f)); dp[7] = (uint)b | ((uint)b << 16);
}

// ---- weight transpose+f16. layer 0 gets paired k-order to match z_p --------
__global__ void k_prep_w(const float* __restrict__ W1, const float* __restrict__ W2,
                         const float* __restrict__ W3, _Float16* __restrict__ Wt) {
  __shared__ _Float16 t[128][130];
  int m = blockIdx.x;  // 0..44 = blk*3+layer
  int blk = m / 3, layer = m % 3;
  const float* src = (layer == 0 ? W1 : layer == 1 ? W2 : W3) + (size_t)blk * 16384;
  int tid = threadIdx.x;
  for (int idx = tid; idx < 16384; idx += 256) {
    int k = idx >> 7, n = idx & 127;
    t[k][n] = (_Float16)src[idx];
  }
  __syncthreads();
  _Float16* dst = Wt + (size_t)m * 16384;
  if (layer == 0) {
    for (int idx = tid; idx < 16384; idx += 256) {
      int n = idx >> 7, p = idx & 127;
      int k = (p >> 1) + 64 * (p & 1);  // paired k-order
      dst[idx] = t[k][n];
    }
  } else {
    for (int idx = tid; idx < 16384; idx += 256) {
      int n = idx >> 7, k = idx & 127;
      dst[idx] = t[k][n];
    }
  }
}

// -------- per-block message+aggregate: packed f16 datapath -------------------
__global__ __launch_bounds__(256) void k_msg(
    const int* __restrict__ off, const uint* __restrict__ srcoff,
    const uint* __restrict__ ea2, const uint* __restrict__ x2p,
    const float* __restrict__ eW, const float* __restrict__ ebias,
    uint* __restrict__ z_p) {
  int wid = (blockIdx.x * blockDim.x + threadIdx.x) >> 6;
  int lane = threadIdx.x & 63;
  if (wid >= N_NODES) return;
  __half2 w01[EDGE_DIM];
#pragma unroll
  for (int k = 0; k < EDGE_DIM; k++)
    w01[k] = __floats2half2_rn(eW[k * N_HIDDEN + lane], eW[k * N_HIDDEN + lane + 64]);
  __half2 bb01 = __floats2half2_rn(ebias[lane], ebias[lane + 64]);
  float acc0 = 0.f, acc1 = 0.f;
  int eBeg = off[wid], eEnd = off[wid + 1];

#define EDGE_COMPUTE(EA, EB, UA)                                               \
  {                                                                            \
    __half2 v = bb01;                                                          \
    v = __hfma2(u2h2((EA).x), w01[0], v);                                      \
    v = __hfma2(u2h2((EA).y), w01[1], v);                                      \
    v = __hfma2(u2h2((EA).z), w01[2], v);                                      \
    v = __hfma2(u2h2((EA).w), w01[3], v);                                      \
    v = __hfma2(u2h2((EB).x), w01[4], v);                                      \
    v = __hfma2(u2h2((EB).y), w01[5], v);                                      \
    v = __hfma2(u2h2((EB).z), w01[6], v);                                      \
    v = __hfma2(u2h2((EB).w), w01[7], v);                                      \
    __half2 mm = __hadd2(u2h2(UA), v);                                         \
    acc0 += fmaxf(__low2float(mm), 0.f);                                       \
    acc1 += fmaxf(__high2float(mm), 0.f);                                      \
  }

  int e = eBeg;
  for (; e + 3 < eEnd; e += 4) {
    uint so0 = srcoff[e], so1 = srcoff[e + 1], so2 = srcoff[e + 2], so3 = srcoff[e + 3];
    uint ua0 = x2p[so0 + lane];
    uint ua1 = x2p[so1 + lane];
    uint ua2 = x2p[so2 + lane];
    uint ua3 = x2p[so3 + lane];
    const uint* ep = ea2 + (size_t)e * 8;
    uint4 a0 = *(const uint4*)(ep + 0), b0 = *(const uint4*)(ep + 4);
    uint4 a1 = *(const uint4*)(ep + 8), b1 = *(const uint4*)(ep + 12);
    uint4 a2 = *(const uint4*)(ep + 16), b2 = *(const uint4*)(ep + 20);
    uint4 a3 = *(const uint4*)(ep + 24), b3 = *(const uint4*)(ep + 28);
    EDGE_COMPUTE(a0, b0, ua0);
    EDGE_COMPUTE(a1, b1, ua1);
    EDGE_COMPUTE(a2, b2, ua2);
    EDGE_COMPUTE(a3, b3, ua3);
  }
  for (; e < eEnd; ++e) {
    uint so = srcoff[e];
    uint ua = x2p[so + lane];
    const uint* ep = ea2 + (size_t)e * 8;
    uint4 a0 = *(const uint4*)(ep + 0), b0 = *(const uint4*)(ep + 4);
    EDGE_COMPUTE(a0, b0, ua);
  }
#undef EDGE_COMPUTE

  uint xp = x2p[(size_t)wid * 64 + lane];
  float z0 = __low2float(u2h2(xp)) + acc0;
  float z1 = __high2float(u2h2(xp)) + acc1;
  uint pk = (uint)f2h_bits(z0) | ((uint)f2h_bits(z1) << 16);
  z_p[(size_t)wid * 64 + lane] = pk;
}

// -------- MFMA MLP: 8 nodes/wave (rows 8-15 duplicate), 32 nodes/block ------
__global__ __launch_bounds__(256) void k_mlp(
    const uint* __restrict__ z_p, const _Float16* __restrict__ Wt,
    const float* __restrict__ b1, const float* __restrict__ b2,
    const float* __restrict__ b3, float* __restrict__ h,
    uint* __restrict__ x2p) {
  __shared__ __align__(16) _Float16 lz[4][16][136];
  int tid = threadIdx.x;
  int w = tid >> 6, lane = tid & 63;
  int l15 = lane & 15, g = lane >> 4;
  int base = blockIdx.x * 32 + w * 8;  // wave's first node
  int nodeA = base + (l15 & 7);        // A-row source (rows 8-15 duplicate 0-7)

  f32x4 acc[8];
  f16x8 a[4];

  // ---- layer 1: A from z_p (paired k-order; Wt layer0 matches) ----
  const _Float16* zrow = (const _Float16*)(z_p + (size_t)nodeA * 64);
#pragma unroll
  for (int kk = 0; kk < 4; kk++) a[kk] = *(const f16x8*)(zrow + kk * 32 + g * 8);
#pragma unroll
  for (int c = 0; c < 8; c++) {
    float bv = b1[c * 16 + l15];
    acc[c] = (f32x4){bv, bv, bv, bv};
  }
#pragma unroll
  for (int c = 0; c < 8; c++) {
#pragma unroll
    for (int kk = 0; kk < 4; kk++) {
      f16x8 bf = *(const f16x8*)(Wt + (size_t)(c * 16 + l15) * 128 + kk * 32 + g * 8);
      acc[c] = __builtin_amdgcn_mfma_f32_16x16x32_f16(a[kk], bf, acc[c], 0, 0, 0);
    }
  }
#pragma unroll
  for (int c = 0; c < 8; c++)
#pragma unroll
    for (int r = 0; r < 4; r++)
      lz[w][4 * g + r][c * 16 + l15] = (_Float16)fmaxf(acc[c][r], 0.f);
  __syncthreads();

  // ---- layer 2 ----
#pragma unroll
  for (int kk = 0; kk < 4; kk++) a[kk] = *(const f16x8*)&lz[w][l15][kk * 32 + g * 8];
#pragma unroll
  for (int c = 0; c < 8; c++) {
    float bv = b2[c * 16 + l15];
    acc[c] = (f32x4){bv, bv, bv, bv};
  }
  {
    const _Float16* W2t = Wt + 16384;
#pragma unroll
    for (int c = 0; c < 8; c++) {
#pragma unroll
      for (int kk = 0; kk < 4; kk++) {
        f16x8 bf = *(const f16x8*)(W2t + (size_t)(c * 16 + l15) * 128 + kk * 32 + g * 8);
        acc[c] = __builtin_amdgcn_mfma_f32_16x16x32_f16(a[kk], bf, acc[c], 0, 0, 0);
      }
    }
  }
  __syncthreads();
#pragma unroll
  for (int c = 0; c < 8; c++)
#pragma unroll
    for (int r = 0; r < 4; r++)
      lz[w][4 * g + r][c * 16 + l15] = (_Float16)fmaxf(acc[c][r], 0.f);
  __syncthreads();

  // ---- layer 3 (no relu) ----
#pragma unroll
  for (int kk = 0; kk < 4; kk++) a[kk] = *(const f16x8*)&lz[w][l15][kk * 32 + g * 8];
#pragma unroll
  for (int c = 0; c < 8; c++) {
    float bv = b3[c * 16 + l15];
    acc[c] = (f32x4){bv, bv, bv, bv};
  }
  {
    const _Float16* W3t = Wt + 32768;
#pragma unroll
    for (int c = 0; c < 8; c++) {
#pragma unroll
      for (int kk = 0; kk < 4; kk++) {
        f16x8 bf = *(const f16x8*)(W3t + (size_t)(c * 16 + l15) * 128 + kk * 32 + g * 8);
        acc[c] = __builtin_amdgcn_mfma_f32_16x16x32_f16(a[kk], bf, acc[c], 0, 0, 0);
      }
    }
  }

  // ---- epilogue: rows 0-7 valid (4g+r<8) ----
  float s1[4] = {0.f, 0.f, 0.f, 0.f}, s2[4] = {0.f, 0.f, 0.f, 0.f};
#pragma unroll
  for (int c = 0; c < 8; c++)
#pragma unroll
    for (int r = 0; r < 4; r++) {
      float v = acc[c][r];
      s1[r] += v;
      s2[r] += v * v;
    }
#pragma unroll
  for (int m = 1; m < 16; m <<= 1)
#pragma unroll
    for (int r = 0; r < 4; r++) {
      s1[r] += __shfl_xor(s1[r], m);
      s2[r] += __shfl_xor(s2[r], m);
    }
  float inv[4];
#pragma unroll
  for (int r = 0; r < 4; r++)
    inv[r] = 1.0f / sqrtf((s2[r] - s1[r] * s1[r] * (1.0f / 128.0f)) * (1.0f / 127.0f));

  float t1[4] = {0.f, 0.f, 0.f, 0.f}, t2[4] = {0.f, 0.f, 0.f, 0.f};
#pragma unroll
  for (int c = 0; c < 8; c++)
#pragma unroll
    for (int r = 0; r < 4; r++) {
      int row = 4 * g + r;
      int nc = base + (row & 7);  // duplicate rows read duplicate h
      float hv = h[(size_t)nc * 128 + c * 16 + l15] + acc[c][r] * inv[r];
      acc[c][r] = hv;
      t1[r] += hv;
      t2[r] += hv * hv;
    }
#pragma unroll
  for (int m = 1; m < 16; m <<= 1)
#pragma unroll
    for (int r = 0; r < 4; r++) {
      t1[r] += __shfl_xor(t1[r], m);
      t2[r] += __shfl_xor(t2[r], m);
    }
  float inv2[4];
#pragma unroll
  for (int r = 0; r < 4; r++)
    inv2[r] = 1.0f / sqrtf((t2[r] - t1[r] * t1[r] * (1.0f / 128.0f)) * (1.0f / 127.0f));

  if (g < 2) {  // rows 0-7 only
#pragma unroll
    for (int c = 0; c < 8; c++)
#pragma unroll
      for (int r = 0; r < 4; r++) {
        int n = base + 4 * g + r;
        h[(size_t)n * 128 + c * 16 + l15] = acc[c][r];
      }
#pragma unroll
    for (int c = 0; c < 4; c++)
#pragma unroll
      for (int r = 0; r < 4; r++) {
        int n = base + 4 * g + r;
        uint pk = (uint)f2h_bits(acc[c][r] * inv2[r]) |
                  ((uint)f2h_bits(acc[c + 4][r] * inv2[r]) << 16);
        x2p[(size_t)n * 64 + c * 16 + l15] = pk;
      }
  }
}

// -------- output --------
__global__ void k_out(const float* __restrict__ h, const float* __restrict__ oW,
                      const float* __restrict__ ob, float* __restrict__ out) {
  int wid = (blockIdx.x * blockDim.x + threadIdx.x) >> 6;
  int lane = threadIdx.x & 63;
  if (wid >= N_NODES) return;
  int c0 = lane, c1 = lane + 64;
  float w0 = 0.f, w1 = 0.f, bsum = 0.f;
#pragma unroll
  for (int j = 0; j < N_BINARY; j++) {
    float sc = (float)(1 << j);
    w0 += oW[c0 * N_BINARY + j] * sc;
    w1 += oW[c1 * N_BINARY + j] * sc;
    bsum += ob[j] * sc;
  }
  size_t o = (size_t)wid * 128;
  float v = h[o + c0] * w0 + h[o + c1] * w1;
#pragma unroll
  for (int m = 1; m < 64; m <<= 1) v += __shfl_xor(v, m);
  if (lane == 0) out[wid] = v * (1.0f / sqrtf(15.0f)) + bsum;
}

extern "C" void kernel_launch(void* const* d_in, const int* in_sizes, int n_in,
                              void* d_out, int out_size, void* d_ws, size_t ws_size,
                              hipStream_t stream) {
  const float* x = (const float*)d_in[0];
  const int* ei = (const int*)d_in[1];
  const float* eattr = (const float*)d_in[2];
  const float* embW = (const float*)d_in[3];
  const float* embB = (const float*)d_in[4];
  const float* edgeW = (const float*)d_in[5];
  const float* edgeB = (const float*)d_in[6];
  const float* W1 = (const float*)d_in[7];
  const float* b1 = (const float*)d_in[8];
  const float* W2 = (const float*)d_in[9];
  const float* b2 = (const float*)d_in[10];
  const float* W3 = (const float*)d_in[11];
  const float* b3 = (const float*)d_in[12];
  const float* outW = (const float*)d_in[13];
  const float* outB = (const float*)d_in[14];
  float* out = (float*)d_out;

  char* base = (char*)d_ws;
  size_t o = 0;
  auto carve = [&](size_t bytes) {
    size_t start = o;
    o = (start + bytes + 255) & ~(size_t)255;
    return (void*)(base + start);
  };
  int* deg = (int*)carve(N_NODES * sizeof(int));
  int* off = (int*)carve((N_NODES + 1) * sizeof(int));
  int* cur = (int*)carve(N_NODES * sizeof(int));
  uint* srcoff = (uint*)carve(N_EDGES * sizeof(uint));
  uint* ea2 = (uint*)carve((size_t)N_EDGES * 8 * sizeof(uint));
  uint* x2p = (uint*)carve((size_t)N_NODES * 64 * sizeof(uint));
  uint* z_p = (uint*)carve((size_t)N_NODES * 64 * sizeof(uint));
  float* h = (float*)carve((size_t)N_NODES * N_HIDDEN * sizeof(float));
  _Float16* Wt = (_Float16*)carve((size_t)45 * 16384 * 2);

  hipMemsetAsync(deg, 0, N_NODES * sizeof(int), stream);
  k_embed<<<N_NODES / 4, 256, 0, stream>>>(x, embW, embB, h, x2p);
  k_count<<<(N_EDGES + 255) / 256, 256, 0, stream>>>(ei, deg);
  k_scan<<<1, 1024, 0, stream>>>(deg, off, cur);
  k_permute<<<(N_EDGES + 255) / 256, 256, 0, stream>>>(ei, eattr, cur, srcoff, ea2);
  k_prep_w<<<45, 256, 0, stream>>>(W1, W2, W3, Wt);

  for (int b = 0; b < N_BLOCKS; b++) {
    k_msg<<<N_NODES / 4, 256, 0, stream>>>(off, srcoff, ea2, x2p,
                                           edgeW + (size_t)b * EDGE_DIM * N_HIDDEN,
                                           edgeB + (size_t)b * N_HIDDEN, z_p);
    k_mlp<<<(N_NODES + 31) / 32, 256, 0, stream>>>(
        z_p, Wt + (size_t)b * 3 * 16384, b1 + (size_t)b * N_HIDDEN,
        b2 + (size_t)b * N_HIDDEN, b3 + (size_t)b * N_HIDDEN, h, x2p);
  }
  k_out<<<N_NODES / 4, 256, 0, stream>>>(h, outW, outB, out);
}

// Round 6
// 1287.555 us; speedup vs baseline: 1.3628x; 1.3628x over previous
//
#include <hip/hip_runtime.h>
#include <hip/hip_bf16.h>
#include <hip/hip_fp16.h>

#define N_NODES 20000
#define N_EDGES 640000
#define N_HIDDEN 128
#define EDGE_DIM 8
#define NODE_DIM 16
#define N_BLOCKS 15
#define N_BINARY 10

typedef __attribute__((ext_vector_type(8))) _Float16 f16x8;
typedef __attribute__((ext_vector_type(4))) float f32x4;
typedef unsigned int uint;
typedef unsigned short ushort;

union U2H {
  uint u;
  __half2 h;
};
static __device__ __forceinline__ __half2 u2h2(uint u) {
  U2H c; c.u = u; return c.h;
}
static __device__ __forceinline__ ushort f2h_bits(float f) {
  union { _Float16 h; ushort u; } c;
  c.h = (_Float16)f;
  return c.u;
}

// ---- embed: h = log(x+1) @ embW + embB ; x2p = packed f16(h/std) -----------
__global__ void k_embed(const float* __restrict__ x, const float* __restrict__ eW,
                        const float* __restrict__ ebias, float* __restrict__ h,
                        uint* __restrict__ x2p) {
  int wid = (blockIdx.x * blockDim.x + threadIdx.x) >> 6;
  int lane = threadIdx.x & 63;
  if (wid >= N_NODES) return;
  float xl[NODE_DIM];
#pragma unroll
  for (int k = 0; k < NODE_DIM; k++) xl[k] = logf(x[wid * NODE_DIM + k] + 1.0f);
  int c0 = lane, c1 = lane + 64;
  float h0 = ebias[c0], h1 = ebias[c1];
#pragma unroll
  for (int k = 0; k < NODE_DIM; k++) {
    h0 += xl[k] * eW[k * N_HIDDEN + c0];
    h1 += xl[k] * eW[k * N_HIDDEN + c1];
  }
  float ss = h0 + h1, s2 = h0 * h0 + h1 * h1;
#pragma unroll
  for (int m = 1; m < 64; m <<= 1) {
    ss += __shfl_xor(ss, m);
    s2 += __shfl_xor(s2, m);
  }
  float var = (s2 - ss * ss * (1.0f / 128.0f)) * (1.0f / 127.0f);
  float inv = 1.0f / sqrtf(var);
  size_t o = (size_t)wid * N_HIDDEN;
  h[o + c0] = h0;
  h[o + c1] = h1;
  uint pk = (uint)f2h_bits(h0 * inv) | ((uint)f2h_bits(h1 * inv) << 16);
  x2p[(size_t)wid * 64 + lane] = pk;
}

// ---------------- CSR build ----------------
__global__ void k_count(const int* __restrict__ ei, int* __restrict__ deg) {
  int e = blockIdx.x * blockDim.x + threadIdx.x;
  if (e < N_EDGES) atomicAdd(&deg[ei[N_EDGES + e]], 1);
}

__global__ __launch_bounds__(1024) void k_scan(const int* __restrict__ deg,
                                               int* __restrict__ off,
                                               int* __restrict__ cur) {
  __shared__ int wsum[16];
  int t = threadIdx.x;
  int lane = t & 63, w = t >> 6;
  int base = t * 20;
  int loc[20];
  int s = 0;
#pragma unroll
  for (int i = 0; i < 20; i++) {
    int idx = base + i;
    int d = (idx < N_NODES) ? deg[idx] : 0;
    loc[i] = s;
    s += d;
  }
  int incl = s;
#pragma unroll
  for (int m = 1; m < 64; m <<= 1) {
    int o = __shfl_up(incl, m);
    if (lane >= m) incl += o;
  }
  if (lane == 63) wsum[w] = incl;
  __syncthreads();
  if (w == 0) {
    int xv = (lane < 16) ? wsum[lane] : 0;
#pragma unroll
    for (int m = 1; m < 16; m <<= 1) {
      int o = __shfl_up(xv, m);
      if (lane >= m) xv += o;
    }
    if (lane < 16) wsum[lane] = xv;
  }
  __syncthreads();
  int woff = (w == 0) ? 0 : wsum[w - 1];
  int texcl = woff + incl - s;
#pragma unroll
  for (int i = 0; i < 20; i++) {
    int idx = base + i;
    if (idx < N_NODES) {
      int v = texcl + loc[i];
      off[idx] = v;
      cur[idx] = v;
    }
  }
  if (t == 0) off[N_NODES] = wsum[15];
}

// permute edges dst-sorted; srcoff = src*64 (dword row offset);
// ea_h[pos] = f16x8 of log(edge_attr+1)  (16 B/edge)
__global__ void k_permute(const int* __restrict__ ei, const float* __restrict__ eattr,
                          int* __restrict__ cur, uint* __restrict__ srcoff,
                          _Float16* __restrict__ ea_h) {
  int e = blockIdx.x * blockDim.x + threadIdx.x;
  if (e >= N_EDGES) return;
  int d = ei[N_EDGES + e];
  int s = ei[e];
  int pos = atomicAdd(&cur[d], 1);
  srcoff[pos] = (uint)s * 64u;
  const float4* ap = (const float4*)(eattr + (size_t)e * 8);
  float4 a0 = ap[0], a1 = ap[1];
  f16x8 r;
  r[0] = (_Float16)logf(a0.x + 1.0f);
  r[1] = (_Float16)logf(a0.y + 1.0f);
  r[2] = (_Float16)logf(a0.z + 1.0f);
  r[3] = (_Float16)logf(a0.w + 1.0f);
  r[4] = (_Float16)logf(a1.x + 1.0f);
  r[5] = (_Float16)logf(a1.y + 1.0f);
  r[6] = (_Float16)logf(a1.z + 1.0f);
  r[7] = (_Float16)logf(a1.w + 1.0f);
  *(f16x8*)(ea_h + (size_t)pos * 8) = r;
}

// ---- weight transpose+f16. layer 0 gets paired k-order to match z_p --------
__global__ void k_prep_w(const float* __restrict__ W1, const float* __restrict__ W2,
                         const float* __restrict__ W3, _Float16* __restrict__ Wt) {
  __shared__ _Float16 t[128][130];
  int m = blockIdx.x;  // 0..44 = blk*3+layer
  int blk = m / 3, layer = m % 3;
  const float* src = (layer == 0 ? W1 : layer == 1 ? W2 : W3) + (size_t)blk * 16384;
  int tid = threadIdx.x;
  for (int idx = tid; idx < 16384; idx += 256) {
    int k = idx >> 7, n = idx & 127;
    t[k][n] = (_Float16)src[idx];
  }
  __syncthreads();
  _Float16* dst = Wt + (size_t)m * 16384;
  if (layer == 0) {
    for (int idx = tid; idx < 16384; idx += 256) {
      int n = idx >> 7, p = idx & 127;
      int k = (p >> 1) + 64 * (p & 1);  // paired k-order
      dst[idx] = t[k][n];
    }
  } else {
    for (int idx = tid; idx < 16384; idx += 256) {
      int n = idx >> 7, k = idx & 127;
      dst[idx] = t[k][n];
    }
  }
}

// -------- message+aggregate: 2 waves per node (edge-range split) -------------
// even wave -> z_p = x2 + aggA ; odd wave -> zB_p = aggB (partial)
__global__ __launch_bounds__(256) void k_msg(
    const int* __restrict__ off, const uint* __restrict__ srcoff,
    const _Float16* __restrict__ ea_h, const uint* __restrict__ x2p,
    const float* __restrict__ eW, const float* __restrict__ ebias,
    uint* __restrict__ z_p, uint* __restrict__ zB_p) {
  int gw = (blockIdx.x * blockDim.x + threadIdx.x) >> 6;  // global wave id
  int lane = threadIdx.x & 63;
  if (gw >= 2 * N_NODES) return;
  int node = gw >> 1;
  int half = gw & 1;
  int nodeU = __builtin_amdgcn_readfirstlane(node);

  // k-paired weights: w0pk[j] = (w_{2j},w_{2j+1}) for c0=lane; w1pk for c1=lane+64
  __half2 w0pk[4], w1pk[4];
#pragma unroll
  for (int j = 0; j < 4; j++) {
    w0pk[j] = __floats2half2_rn(eW[(2 * j) * N_HIDDEN + lane],
                                eW[(2 * j + 1) * N_HIDDEN + lane]);
    w1pk[j] = __floats2half2_rn(eW[(2 * j) * N_HIDDEN + lane + 64],
                                eW[(2 * j + 1) * N_HIDDEN + lane + 64]);
  }
  __half2 bb01 = __floats2half2_rn(ebias[lane], ebias[lane + 64]);

  int beg = off[nodeU], end = off[nodeU + 1];
  int mid = (beg + end) >> 1;
  int eBeg = half ? mid : beg;
  int eEnd = half ? end : mid;

  float acc0 = 0.f, acc1 = 0.f;

#define EDGE_COMPUTE(EV, UA)                                                   \
  {                                                                            \
    __half2 pA = __hmul2(u2h2((EV).x), w0pk[0]);                               \
    pA = __hfma2(u2h2((EV).y), w0pk[1], pA);                                   \
    pA = __hfma2(u2h2((EV).z), w0pk[2], pA);                                   \
    pA = __hfma2(u2h2((EV).w), w0pk[3], pA);                                   \
    __half2 pB = __hmul2(u2h2((EV).x), w1pk[0]);                               \
    pB = __hfma2(u2h2((EV).y), w1pk[1], pB);                                   \
    pB = __hfma2(u2h2((EV).z), w1pk[2], pB);                                   \
    pB = __hfma2(u2h2((EV).w), w1pk[3], pB);                                   \
    __half v0 = __hadd(__low2half(pA), __high2half(pA));                       \
    __half v1 = __hadd(__low2half(pB), __high2half(pB));                       \
    __half2 mm = __hadd2(__halves2half2(v0, v1), __hadd2(u2h2(UA), bb01));     \
    acc0 += fmaxf(__low2float(mm), 0.f);                                       \
    acc1 += fmaxf(__high2float(mm), 0.f);                                      \
  }

  int e = eBeg;
  for (; e + 3 < eEnd; e += 4) {
    int eU = __builtin_amdgcn_readfirstlane(e);
    uint so0 = srcoff[eU], so1 = srcoff[eU + 1];
    uint so2 = srcoff[eU + 2], so3 = srcoff[eU + 3];
    uint4 ev0 = *(const uint4*)(ea_h + (size_t)eU * 8);
    uint4 ev1 = *(const uint4*)(ea_h + (size_t)(eU + 1) * 8);
    uint4 ev2 = *(const uint4*)(ea_h + (size_t)(eU + 2) * 8);
    uint4 ev3 = *(const uint4*)(ea_h + (size_t)(eU + 3) * 8);
    uint ua0 = x2p[so0 + lane];
    uint ua1 = x2p[so1 + lane];
    uint ua2 = x2p[so2 + lane];
    uint ua3 = x2p[so3 + lane];
    EDGE_COMPUTE(ev0, ua0);
    EDGE_COMPUTE(ev1, ua1);
    EDGE_COMPUTE(ev2, ua2);
    EDGE_COMPUTE(ev3, ua3);
  }
  for (; e < eEnd; ++e) {
    int eU = __builtin_amdgcn_readfirstlane(e);
    uint so = srcoff[eU];
    uint4 ev = *(const uint4*)(ea_h + (size_t)eU * 8);
    uint ua = x2p[so + lane];
    EDGE_COMPUTE(ev, ua);
  }
#undef EDGE_COMPUTE

  if (half == 0) {
    uint xp = x2p[(size_t)node * 64 + lane];
    float z0 = __low2float(u2h2(xp)) + acc0;
    float z1 = __high2float(u2h2(xp)) + acc1;
    uint pk = (uint)f2h_bits(z0) | ((uint)f2h_bits(z1) << 16);
    z_p[(size_t)node * 64 + lane] = pk;
  } else {
    uint pk = (uint)f2h_bits(acc0) | ((uint)f2h_bits(acc1) << 16);
    zB_p[(size_t)node * 64 + lane] = pk;
  }
}

// -------- MFMA MLP: 64 nodes/block, 4 waves, wave owns 16 rows (R3 geom) ----
__global__ __launch_bounds__(256) void k_mlp(
    const uint* __restrict__ z_p, const uint* __restrict__ zB_p,
    const _Float16* __restrict__ Wt, const float* __restrict__ b1,
    const float* __restrict__ b2, const float* __restrict__ b3,
    float* __restrict__ h, uint* __restrict__ x2p) {
  __shared__ __align__(16) _Float16 lz[4][16][136];
  int tid = threadIdx.x;
  int w = tid >> 6, lane = tid & 63;
  int l15 = lane & 15, g = lane >> 4;
  int g0 = blockIdx.x * 64;
  int nodeA = g0 + w * 16 + l15;
  int nodeAc = min(nodeA, N_NODES - 1);

  f32x4 acc[8];
  f16x8 a[4];

  // ---- layer 1: A = z_p + zB_p (paired k-order; Wt layer0 matches) ----
  const _Float16* zrowA = (const _Float16*)(z_p + (size_t)nodeAc * 64);
  const _Float16* zrowB = (const _Float16*)(zB_p + (size_t)nodeAc * 64);
#pragma unroll
  for (int kk = 0; kk < 4; kk++) {
    f16x8 za = *(const f16x8*)(zrowA + kk * 32 + g * 8);
    f16x8 zb = *(const f16x8*)(zrowB + kk * 32 + g * 8);
    a[kk] = za + zb;
  }
#pragma unroll
  for (int c = 0; c < 8; c++) {
    float bv = b1[c * 16 + l15];
    acc[c] = (f32x4){bv, bv, bv, bv};
  }
#pragma unroll
  for (int c = 0; c < 8; c++) {
#pragma unroll
    for (int kk = 0; kk < 4; kk++) {
      f16x8 bf = *(const f16x8*)(Wt + (size_t)(c * 16 + l15) * 128 + kk * 32 + g * 8);
      acc[c] = __builtin_amdgcn_mfma_f32_16x16x32_f16(a[kk], bf, acc[c], 0, 0, 0);
    }
  }
#pragma unroll
  for (int c = 0; c < 8; c++)
#pragma unroll
    for (int r = 0; r < 4; r++)
      lz[w][4 * g + r][c * 16 + l15] = (_Float16)fmaxf(acc[c][r], 0.f);
  __syncthreads();

  // ---- layer 2 ----
#pragma unroll
  for (int kk = 0; kk < 4; kk++) a[kk] = *(const f16x8*)&lz[w][l15][kk * 32 + g * 8];
#pragma unroll
  for (int c = 0; c < 8; c++) {
    float bv = b2[c * 16 + l15];
    acc[c] = (f32x4){bv, bv, bv, bv};
  }
  {
    const _Float16* W2t = Wt + 16384;
#pragma unroll
    for (int c = 0; c < 8; c++) {
#pragma unroll
      for (int kk = 0; kk < 4; kk++) {
        f16x8 bf = *(const f16x8*)(W2t + (size_t)(c * 16 + l15) * 128 + kk * 32 + g * 8);
        acc[c] = __builtin_amdgcn_mfma_f32_16x16x32_f16(a[kk], bf, acc[c], 0, 0, 0);
      }
    }
  }
  __syncthreads();
#pragma unroll
  for (int c = 0; c < 8; c++)
#pragma unroll
    for (int r = 0; r < 4; r++)
      lz[w][4 * g + r][c * 16 + l15] = (_Float16)fmaxf(acc[c][r], 0.f);
  __syncthreads();

  // ---- layer 3 (no relu) ----
#pragma unroll
  for (int kk = 0; kk < 4; kk++) a[kk] = *(const f16x8*)&lz[w][l15][kk * 32 + g * 8];
#pragma unroll
  for (int c = 0; c < 8; c++) {
    float bv = b3[c * 16 + l15];
    acc[c] = (f32x4){bv, bv, bv, bv};
  }
  {
    const _Float16* W3t = Wt + 32768;
#pragma unroll
    for (int c = 0; c < 8; c++) {
#pragma unroll
      for (int kk = 0; kk < 4; kk++) {
        f16x8 bf = *(const f16x8*)(W3t + (size_t)(c * 16 + l15) * 128 + kk * 32 + g * 8);
        acc[c] = __builtin_amdgcn_mfma_f32_16x16x32_f16(a[kk], bf, acc[c], 0, 0, 0);
      }
    }
  }

  // ---- epilogue: y = z3/std; h += y; x2p = packed f16(h/std) ----
  float s1[4] = {0.f, 0.f, 0.f, 0.f}, s2[4] = {0.f, 0.f, 0.f, 0.f};
#pragma unroll
  for (int c = 0; c < 8; c++)
#pragma unroll
    for (int r = 0; r < 4; r++) {
      float v = acc[c][r];
      s1[r] += v;
      s2[r] += v * v;
    }
#pragma unroll
  for (int m = 1; m < 16; m <<= 1)
#pragma unroll
    for (int r = 0; r < 4; r++) {
      s1[r] += __shfl_xor(s1[r], m);
      s2[r] += __shfl_xor(s2[r], m);
    }
  float inv[4];
#pragma unroll
  for (int r = 0; r < 4; r++)
    inv[r] = 1.0f / sqrtf((s2[r] - s1[r] * s1[r] * (1.0f / 128.0f)) * (1.0f / 127.0f));

  int nodeE = g0 + w * 16 + 4 * g;
  float t1[4] = {0.f, 0.f, 0.f, 0.f}, t2[4] = {0.f, 0.f, 0.f, 0.f};
#pragma unroll
  for (int c = 0; c < 8; c++)
#pragma unroll
    for (int r = 0; r < 4; r++) {
      int n = nodeE + r;
      int nc = min(n, N_NODES - 1);
      float hv = h[(size_t)nc * 128 + c * 16 + l15] + acc[c][r] * inv[r];
      acc[c][r] = hv;
      t1[r] += hv;
      t2[r] += hv * hv;
    }
#pragma unroll
  for (int m = 1; m < 16; m <<= 1)
#pragma unroll
    for (int r = 0; r < 4; r++) {
      t1[r] += __shfl_xor(t1[r], m);
      t2[r] += __shfl_xor(t2[r], m);
    }
  float inv2[4];
#pragma unroll
  for (int r = 0; r < 4; r++)
    inv2[r] = 1.0f / sqrtf((t2[r] - t1[r] * t1[r] * (1.0f / 128.0f)) * (1.0f / 127.0f));

#pragma unroll
  for (int c = 0; c < 8; c++)
#pragma unroll
    for (int r = 0; r < 4; r++) {
      int n = nodeE + r;
      if (n < N_NODES) h[(size_t)n * 128 + c * 16 + l15] = acc[c][r];
    }
#pragma unroll
  for (int c = 0; c < 4; c++)
#pragma unroll
    for (int r = 0; r < 4; r++) {
      int n = nodeE + r;
      if (n < N_NODES) {
        uint pk = (uint)f2h_bits(acc[c][r] * inv2[r]) |
                  ((uint)f2h_bits(acc[c + 4][r] * inv2[r]) << 16);
        x2p[(size_t)n * 64 + c * 16 + l15] = pk;
      }
    }
}

// -------- output --------
__global__ void k_out(const float* __restrict__ h, const float* __restrict__ oW,
                      const float* __restrict__ ob, float* __restrict__ out) {
  int wid = (blockIdx.x * blockDim.x + threadIdx.x) >> 6;
  int lane = threadIdx.x & 63;
  if (wid >= N_NODES) return;
  int c0 = lane, c1 = lane + 64;
  float w0 = 0.f, w1 = 0.f, bsum = 0.f;
#pragma unroll
  for (int j = 0; j < N_BINARY; j++) {
    float sc = (float)(1 << j);
    w0 += oW[c0 * N_BINARY + j] * sc;
    w1 += oW[c1 * N_BINARY + j] * sc;
    bsum += ob[j] * sc;
  }
  size_t o = (size_t)wid * 128;
  float v = h[o + c0] * w0 + h[o + c1] * w1;
#pragma unroll
  for (int m = 1; m < 64; m <<= 1) v += __shfl_xor(v, m);
  if (lane == 0) out[wid] = v * (1.0f / sqrtf(15.0f)) + bsum;
}

extern "C" void kernel_launch(void* const* d_in, const int* in_sizes, int n_in,
                              void* d_out, int out_size, void* d_ws, size_t ws_size,
                              hipStream_t stream) {
  const float* x = (const float*)d_in[0];
  const int* ei = (const int*)d_in[1];
  const float* eattr = (const float*)d_in[2];
  const float* embW = (const float*)d_in[3];
  const float* embB = (const float*)d_in[4];
  const float* edgeW = (const float*)d_in[5];
  const float* edgeB = (const float*)d_in[6];
  const float* W1 = (const float*)d_in[7];
  const float* b1 = (const float*)d_in[8];
  const float* W2 = (const float*)d_in[9];
  const float* b2 = (const float*)d_in[10];
  const float* W3 = (const float*)d_in[11];
  const float* b3 = (const float*)d_in[12];
  const float* outW = (const float*)d_in[13];
  const float* outB = (const float*)d_in[14];
  float* out = (float*)d_out;

  char* base = (char*)d_ws;
  size_t o = 0;
  auto carve = [&](size_t bytes) {
    size_t start = o;
    o = (start + bytes + 255) & ~(size_t)255;
    return (void*)(base + start);
  };
  int* deg = (int*)carve(N_NODES * sizeof(int));
  int* off = (int*)carve((N_NODES + 1) * sizeof(int));
  int* cur = (int*)carve(N_NODES * sizeof(int));
  uint* srcoff = (uint*)carve(N_EDGES * sizeof(uint));
  _Float16* ea_h = (_Float16*)carve((size_t)N_EDGES * EDGE_DIM * 2);
  uint* x2p = (uint*)carve((size_t)N_NODES * 64 * sizeof(uint));
  uint* z_p = (uint*)carve((size_t)N_NODES * 64 * sizeof(uint));
  uint* zB_p = (uint*)carve((size_t)N_NODES * 64 * sizeof(uint));
  float* h = (float*)carve((size_t)N_NODES * N_HIDDEN * sizeof(float));
  _Float16* Wt = (_Float16*)carve((size_t)45 * 16384 * 2);

  hipMemsetAsync(deg, 0, N_NODES * sizeof(int), stream);
  k_embed<<<N_NODES / 4, 256, 0, stream>>>(x, embW, embB, h, x2p);
  k_count<<<(N_EDGES + 255) / 256, 256, 0, stream>>>(ei, deg);
  k_scan<<<1, 1024, 0, stream>>>(deg, off, cur);
  k_permute<<<(N_EDGES + 255) / 256, 256, 0, stream>>>(ei, eattr, cur, srcoff, ea_h);
  k_prep_w<<<45, 256, 0, stream>>>(W1, W2, W3, Wt);

  for (int b = 0; b < N_BLOCKS; b++) {
    k_msg<<<(2 * N_NODES + 3) / 4, 256, 0, stream>>>(
        off, srcoff, ea_h, x2p, edgeW + (size_t)b * EDGE_DIM * N_HIDDEN,
        edgeB + (size_t)b * N_HIDDEN, z_p, zB_p);
    k_mlp<<<(N_NODES + 63) / 64, 256, 0, stream>>>(
        z_p, zB_p, Wt + (size_t)b * 3 * 16384, b1 + (size_t)b * N_HIDDEN,
        b2 + (size_t)b * N_HIDDEN, b3 + (size_t)b * N_HIDDEN, h, x2p);
  }
  k_out<<<N_NODES / 4, 256, 0, stream>>>(h, outW, outB, out);
}